// Round 6
// baseline (346.165 us; speedup 1.0000x reference)
//
#include <hip/hip_runtime.h>
#include <cstdint>
#include <cstddef>

// ---------------------------------------------------------------------------
// DetCenterDense: fused conv3x3(128->64)+ReLU -> 4x conv1x1 heads (20 ch total,
// sigmoid on last 4) over [4,128,512,512] fp32, NCHW. bf16 MFMA implicit GEMM.
// R6: two-kernel plan. prep_t transposes feature to [oct][h][w][8cin] bf16 in
//     d_ws (per batch); main kernel stages A and B entirely via
//     global_load_lds DMA (no staging VALU / prefetch regs), 512-thr blocks,
//     16 waves/CU, counted vmcnt(5). Fallback to R4 kernel if ws too small.
// ---------------------------------------------------------------------------

typedef __bf16 bf16x8 __attribute__((ext_vector_type(8)));
typedef __bf16 bf16x4 __attribute__((ext_vector_type(4)));
typedef float f32x16 __attribute__((ext_vector_type(16)));
typedef float f32x4v __attribute__((ext_vector_type(4)));
typedef float f32x2v __attribute__((ext_vector_type(2)));

#define CHW (512 * 512)
#define ZB_OFF  147456          // 64B zero page
#define FT_OFF  262144          // feat_t slice (one batch): 16*512*512*16B
#define FT_BYTES 67108864ull

// ---------------------------------------------------------------------------
// Prepass W: repack w_shared [64][128][3][3] fp32 -> bf16:
// ws3 [hc(8)][tap(9)][hw(2)][och(64)][8 bf16]  (18432 B per hc)
// ---------------------------------------------------------------------------
__global__ void prep_w_kernel(const float* __restrict__ w, __bf16* __restrict__ ws3) {
    int idx = blockIdx.x * 256 + threadIdx.x;
    if (idx >= 64 * 128 * 9) return;
    int tap = idx % 9;
    int cin = (idx / 9) % 128;
    int och = idx / (9 * 128);
    int hc = cin >> 4;
    int hw = (cin >> 3) & 1;
    int j  = cin & 7;
    int dst = (((hc * 9 + tap) * 2 + hw) * 64 + och) * 8 + j;
    ws3[dst] = (__bf16)w[idx];
}

// ---------------------------------------------------------------------------
// Prepass T (per batch): feature fp32 NCHW -> feat_t bf16 [16 oct][512 h][512 w][8 cin]
// granule 16B = 8 cin at one (h,w). Coalesced loads and stores.
// ---------------------------------------------------------------------------
__global__ __launch_bounds__(256)
void prep_t_kernel(const float* __restrict__ feature, __bf16* __restrict__ ft, int bz) {
    const int b   = blockIdx.x;          // 4096 = 16 oct x 256 h-pairs
    const int oct = b & 15;
    const int hp  = b >> 4;
    const int tid = threadIdx.x;
    const int h   = hp * 2 + (tid >> 7);
    const int w4  = (tid & 127) * 4;
    const float* src = feature + (size_t)(bz * 128 + oct * 8) * CHW + h * 512 + w4;
    f32x4v R[8];
    #pragma unroll
    for (int j = 0; j < 8; ++j) R[j] = *(const f32x4v*)(src + (size_t)j * CHW);
    #pragma unroll
    for (int k = 0; k < 4; ++k) {
        bf16x8 g;
        #pragma unroll
        for (int j = 0; j < 8; ++j) g[j] = (__bf16)R[j][k];
        *(bf16x8*)(ft + ((size_t)(oct * 512 + h) * 512 + (w4 + k)) * 8) = g;
    }
}

// ---------------------------------------------------------------------------
// Main kernel (per batch). Grid 512 blocks x 512 threads (8 waves).
// Block tile: 4 out-rows x 128 cols (512 px). Wave: 64 px x 64 och.
// LDS: A dbuf 2x[6 row][2 oct][132 slot][16B] @0/25344; B @50688 [18432];
//      wc @69120 [4096]; bias @73216 [128].  73344 B -> 2 blocks/CU.
// All staging via global_load_lds: per wave per hc exactly 5 A-DMA + 3 B-DMA
// (overlap/dummy chunks pad to uniform counts) -> counted vmcnt(5).
// ---------------------------------------------------------------------------
__global__ __launch_bounds__(512, 4)
void det_main_t(const char* __restrict__ ft, const char* __restrict__ zbuf,
                const __bf16* __restrict__ ws3,
                const float* __restrict__ w_cls, const float* __restrict__ b_cls,
                const float* __restrict__ w_box, const float* __restrict__ b_box,
                const float* __restrict__ w_dir, const float* __restrict__ b_dir,
                const float* __restrict__ w_scr, const float* __restrict__ b_scr,
                float* __restrict__ out, int bz) {
    __shared__ __align__(1024) char s_all[73344];

    const int tid  = threadIdx.x;
    const int lane = tid & 63;
    const int wave = tid >> 6;       // 0..7
    const int l31  = lane & 31;
    const int hw   = lane >> 5;
    const int wrow = wave >> 1;      // 0..3 output row
    const int wch  = wave & 1;       // 0..1 col half

    // XCD swizzle: 512 blocks -> 8 chunks of 64 (vertical strips share halo in L2)
    const int bid = blockIdx.x;
    const int wg  = (bid & 7) * 64 + (bid >> 3);
    const int w_t = wg >> 7;         // 0..3
    const int h_t = wg & 127;        // 0..127
    const int h0  = h_t * 4;
    const int w0  = w_t * 128;

    // ---- A-DMA chunk table: 36 real chunks (12 row-oct x {s0-63, s64-127, s66-129})
    //      + 4 dummies (dup of 0..3) = 40 -> 5 per wave. Per-lane OOB -> zbuf.
    int a_lds[5]; const char* a_src[5]; int a_step[5];
    #pragma unroll
    for (int i = 0; i < 5; ++i) {
        int e = wave * 5 + i; if (e >= 36) e -= 36;
        int ro = e / 3, c3 = e - ro * 3;
        int row = ro >> 1, oct = ro & 1;
        int start = (c3 == 0) ? 0 : (c3 == 1) ? 64 : 66;
        a_lds[i] = (row * 2 + oct) * 2112 + start * 16;
        int hrow = h0 - 1 + row;
        int wv   = w0 - 1 + start + lane;
        bool ok = ((unsigned)hrow < 512u) && ((unsigned)wv < 512u);
        long off = ((long)(oct * 512 + (ok ? hrow : 0)) * 512 + (ok ? wv : 0)) * 16;
        a_src[i]  = ok ? (ft + off) : zbuf;
        a_step[i] = ok ? (2 * CHW * 16) : 0;     // +2 cin-octet planes per hc
    }
    // ---- B-DMA: 18 real chunks of 64 granules + 6 dups = 24 -> 3 per wave.
    int b_lds[3]; const char* b_src[3];
    #pragma unroll
    for (int i = 0; i < 3; ++i) {
        int j = wave * 3 + i; if (j >= 18) j -= 18;
        b_lds[i] = 50688 + j * 1024;
        b_src[i] = (const char*)ws3 + j * 1024 + lane * 16;
    }

    auto issueA = [&](int hc, int buf) {
        #pragma unroll
        for (int i = 0; i < 5; ++i)
            __builtin_amdgcn_global_load_lds(
                (const __attribute__((address_space(1))) void*)(a_src[i] + (long)hc * a_step[i]),
                (__attribute__((address_space(3))) void*)(s_all + buf * 25344 + a_lds[i]),
                16, 0, 0);
    };
    auto issueB = [&](int hc) {
        #pragma unroll
        for (int i = 0; i < 3; ++i)
            __builtin_amdgcn_global_load_lds(
                (const __attribute__((address_space(1))) void*)(b_src[i] + hc * 18432),
                (__attribute__((address_space(3))) void*)(s_all + b_lds[i]),
                16, 0, 0);
    };

    // ---- stage 1x1-head weights (bf16, row-swizzled) + bias into LDS ----
    if (tid < 256) {
        char* s_wc = s_all + 69120;
        int och = tid >> 3;            // 0..31
        int j8  = (tid & 7) * 8;
        float v[8];
        if (och < 20) {
            const float* src = (och < 2)  ? (w_cls + och * 64)
                             : (och < 8)  ? (w_box + (och - 2) * 64)
                             : (och < 16) ? (w_dir + (och - 8) * 64)
                                          : (w_scr + (och - 16) * 64);
            #pragma unroll
            for (int j = 0; j < 8; ++j) v[j] = src[j8 + j];
        } else {
            #pragma unroll
            for (int j = 0; j < 8; ++j) v[j] = 0.f;
        }
        bf16x8 wv;
        #pragma unroll
        for (int j = 0; j < 8; ++j) wv[j] = (__bf16)v[j];
        *(bf16x8*)(s_wc + och * 128 + ((j8 * 2) ^ ((och & 7) << 4))) = wv;
        if (tid < 32) {
            float* s_bias = (float*)(s_all + 73216);
            s_bias[tid] = (tid < 2)  ? b_cls[tid]
                        : (tid < 8)  ? b_box[tid - 2]
                        : (tid < 16) ? b_dir[tid - 8]
                        : (tid < 20) ? b_scr[tid - 16] : 0.f;
        }
    }

    f32x16 zero16;
    #pragma unroll
    for (int e = 0; e < 16; ++e) zero16[e] = 0.f;
    f32x16 acc[2][2];
    acc[0][0] = zero16; acc[0][1] = zero16; acc[1][0] = zero16; acc[1][1] = zero16;

    auto mfma_phase = [&](int buf) {
        const char* ab = s_all + buf * 25344 + wrow * 4224 + hw * 2112
                       + (wch * 64 + l31) * 16;
        const char* bb = s_all + 50688 + hw * 1024 + l31 * 16;
        #pragma unroll
        for (int tap = 0; tap < 9; ++tap) {
            const int kh = tap / 3, kw = tap % 3;
            bf16x8 Bf0 = *(const bf16x8*)(bb + tap * 2048);
            bf16x8 Bf1 = *(const bf16x8*)(bb + tap * 2048 + 512);
            bf16x8 Af0 = *(const bf16x8*)(ab + kh * 4224 + kw * 16);
            bf16x8 Af1 = *(const bf16x8*)(ab + kh * 4224 + kw * 16 + 512);
            __builtin_amdgcn_s_setprio(1);
            acc[0][0] = __builtin_amdgcn_mfma_f32_32x32x16_bf16(Af0, Bf0, acc[0][0], 0, 0, 0);
            acc[0][1] = __builtin_amdgcn_mfma_f32_32x32x16_bf16(Af0, Bf1, acc[0][1], 0, 0, 0);
            acc[1][0] = __builtin_amdgcn_mfma_f32_32x32x16_bf16(Af1, Bf0, acc[1][0], 0, 0, 0);
            acc[1][1] = __builtin_amdgcn_mfma_f32_32x32x16_bf16(Af1, Bf1, acc[1][1], 0, 0, 0);
            __builtin_amdgcn_s_setprio(0);
        }
    };

    // ---- prologue: A(0)->buf0, B(0), A(1)->buf1; drain A0+B0, leave A1 ----
    issueA(0, 0);
    issueB(0);
    issueA(1, 1);
    asm volatile("s_waitcnt vmcnt(5) lgkmcnt(0)" ::: "memory");
    __builtin_amdgcn_s_barrier();
    __builtin_amdgcn_sched_barrier(0);

    // ---- main loop: 8 half-chunks of 16 cin ----
    #pragma unroll 1
    for (int h = 0; h < 8; ++h) {
        mfma_phase(h & 1);
        __builtin_amdgcn_sched_barrier(0);
        __builtin_amdgcn_s_barrier();        // everyone done reading A[h&1], B(h)
        __builtin_amdgcn_sched_barrier(0);
        if (h == 7) break;
        issueB(h + 1);                       // overwrite B
        if (h < 6) issueA(h + 2, h & 1);     // overwrite A[h&1]
        if (h < 6) asm volatile("s_waitcnt vmcnt(5)" ::: "memory");  // A(h+1),B(h+1) done
        else       asm volatile("s_waitcnt vmcnt(0)" ::: "memory");
        __builtin_amdgcn_s_barrier();
        __builtin_amdgcn_sched_barrier(0);
    }

    // ---- ReLU -> bf16 X tile in LDS (reuse A/B region), px-XOR swizzled ----
    __bf16* X = (__bf16*)s_all;              // [512 px][64 ch] = 64 KB
    #pragma unroll
    for (int mt = 0; mt < 2; ++mt) {
        #pragma unroll
        for (int nt = 0; nt < 2; ++nt) {
            #pragma unroll
            for (int r = 0; r < 16; ++r) {
                float v = fmaxf(acc[mt][nt][r], 0.f);
                int mrow = (r & 3) + 8 * (r >> 2) + 4 * hw;
                int px   = wrow * 128 + wch * 64 + mt * 32 + mrow;
                int chn  = nt * 32 + l31;
                *(__bf16*)((char*)X + px * 128 + ((chn * 2) ^ ((px & 7) << 4))) = (__bf16)v;
            }
        }
    }
    // wave-local write->read; compiler orders via lgkmcnt

    // ---- stage 2: out[och(20->32)][64 px per wave] = Wc @ X, K=64 ----
    const char* s_wc = s_all + 69120;
    const float* s_bias = (const float*)(s_all + 73216);
    f32x16 acc2[2];
    acc2[0] = zero16; acc2[1] = zero16;
    #pragma unroll
    for (int ks = 0; ks < 4; ++ks) {
        int ch0 = ks * 16 + hw * 8;
        bf16x8 a2 = *(const bf16x8*)(s_wc + l31 * 128 + ((ch0 * 2) ^ ((l31 & 7) << 4)));
        #pragma unroll
        for (int pt = 0; pt < 2; ++pt) {
            int px = wave * 64 + pt * 32 + l31;
            bf16x8 b2 = *(const bf16x8*)((const char*)X + px * 128 + ((ch0 * 2) ^ ((px & 7) << 4)));
            acc2[pt] = __builtin_amdgcn_mfma_f32_32x32x16_bf16(a2, b2, acc2[pt], 0, 0, 0);
        }
    }

    // ---- epilogue: bias, sigmoid on och 16..19, coalesced stores ----
    const int hrow = h0 + wrow;
    #pragma unroll
    for (int pt = 0; pt < 2; ++pt) {
        int wcol = w0 + wch * 64 + pt * 32 + l31;
        #pragma unroll
        for (int r = 0; r < 16; ++r) {
            int och = (r & 3) + 8 * (r >> 2) + 4 * hw;
            if (och < 20) {
                float v = acc2[pt][r] + s_bias[och];
                if (och >= 16) v = 1.f / (1.f + __expf(-v));
                out[(((size_t)bz * 20 + och) * 512 + hrow) * 512 + wcol] = v;
            }
        }
    }
}

// ---------------------------------------------------------------------------
// Fallback (R4 kernel, verbatim): used when ws_size can't hold feat_t.
// ---------------------------------------------------------------------------
__device__ __forceinline__ int swz(int s, int o) {
    int lin = (s << 5) | (o << 4);
    return lin ^ ((lin >> 1) & 0x10) ^ ((lin >> 2) & 0x60);
}
#define A_OFF(p)  ((p) ? 16896 : 0)
#define B_OFF(p)  (33792 + ((p) ? 18432 : 0))

__global__ __launch_bounds__(256, 2)
void det_main_fb(const float* __restrict__ feature,
                 const __bf16* __restrict__ ws3,
                 const float* __restrict__ w_cls, const float* __restrict__ b_cls,
                 const float* __restrict__ w_box, const float* __restrict__ b_box,
                 const float* __restrict__ w_dir, const float* __restrict__ b_dir,
                 const float* __restrict__ w_scr, const float* __restrict__ b_scr,
                 float* __restrict__ out) {
    __shared__ __align__(1024) char s_all[74880];
    const int tid  = threadIdx.x;
    const int lane = tid & 63;
    const int wave = tid >> 6;
    const int l31  = lane & 31;
    const int hw   = lane >> 5;
    const int wrow = wave >> 1;
    const int wcb  = (wave & 1) * 64;
    const int bid = blockIdx.x;
    const int wg  = (bid & 7) * 512 + (bid >> 3);
    const int ck  = wg >> 9;
    const int bz  = ck >> 1;
    const int rem = wg & 511;
    const int h0  = (rem >> 1) * 2;
    const int w0  = ((ck & 1) * 2 + (rem & 1)) * 128;
    const int m_hw  = tid & 1;
    const int m_q   = (tid >> 1) & 31;
    const int m_row = tid >> 6;
    const int m_h   = h0 - 1 + m_row;
    const bool m_ok = (unsigned)m_h < 512u;
    const float* m_base = feature + (size_t)(bz * 128 + m_hw * 8) * CHW
                        + (size_t)(m_ok ? m_h : 0) * 512 + (w0 + 4 * m_q);
    const bool e_on = (tid & 1) == 0;
    const int e_idx = tid >> 1;
    const int e_ee  = (e_idx >> 6) & 1;
    const int e_row = (e_idx >> 4) & 3;
    const int e_cin = e_idx & 15;
    const int e_h   = h0 - 1 + e_row;
    const int e_w   = e_ee ? (w0 + 128) : (w0 - 2);
    const bool e_ok = ((unsigned)e_h < 512u) && ((unsigned)e_w < 511u);
    const float* e_base = feature + (size_t)(bz * 128 + e_cin) * CHW
                        + (size_t)(e_ok ? e_h : 0) * 512 + (e_ok ? e_w : 0);
    {
        char* s_wc = s_all + 70656;
        float* s_bias = (float*)(s_all + 74752);
        int och = tid >> 3;
        int j8  = (tid & 7) * 8;
        float v[8];
        if (och < 20) {
            const float* src = (och < 2)  ? (w_cls + och * 64)
                             : (och < 8)  ? (w_box + (och - 2) * 64)
                             : (och < 16) ? (w_dir + (och - 8) * 64)
                                          : (w_scr + (och - 16) * 64);
            #pragma unroll
            for (int j = 0; j < 8; ++j) v[j] = src[j8 + j];
        } else {
            #pragma unroll
            for (int j = 0; j < 8; ++j) v[j] = 0.f;
        }
        bf16x8 wv;
        #pragma unroll
        for (int j = 0; j < 8; ++j) wv[j] = (__bf16)v[j];
        *(bf16x8*)(s_wc + och * 128 + ((j8 * 2) ^ ((och & 7) << 4))) = wv;
        if (tid < 32) {
            s_bias[tid] = (tid < 2)  ? b_cls[tid]
                        : (tid < 8)  ? b_box[tid - 2]
                        : (tid < 16) ? b_dir[tid - 8]
                        : (tid < 20) ? b_scr[tid - 16] : 0.f;
        }
    }
    f32x4v Ra[8], Rb[8];
    f32x2v Ea, Eb;
    auto issueA = [&](int hc, f32x4v (&R)[8], f32x2v& E) {
        const float* p = m_base + (size_t)(hc * 16) * CHW;
        #pragma unroll
        for (int j = 0; j < 8; ++j) R[j] = *(const f32x4v*)(p + (size_t)j * CHW);
        if (e_on) E = *(const f32x2v*)(e_base + (size_t)(hc * 16) * CHW);
    };
    auto writeA = [&](int hc, f32x4v (&R)[8], f32x2v& E) {
        char* ab = s_all + A_OFF(hc & 1);
        #pragma unroll
        for (int k = 0; k < 4; ++k) {
            bf16x8 g;
            #pragma unroll
            for (int j = 0; j < 8; ++j) g[j] = (__bf16)(m_ok ? R[j][k] : 0.f);
            *(bf16x8*)(ab + m_row * 4224 + swz(2 + 4 * m_q + k, m_hw)) = g;
        }
        if (e_on) {
            char* b2 = ab + e_row * 4224 + (e_cin & 7) * 2;
            int s0 = e_ee ? 130 : 0;
            *(__bf16*)(b2 + swz(s0,     e_cin >> 3)) = (__bf16)(e_ok ? E[0] : 0.f);
            *(__bf16*)(b2 + swz(s0 + 1, e_cin >> 3)) = (__bf16)(e_ok ? E[1] : 0.f);
        }
    };
    auto issueB = [&](int hc) {
        char* bb = s_all + B_OFF(hc & 1);
        const char* src = (const char*)ws3 + hc * 18432;
        #pragma unroll
        for (int i = 0; i < 4; ++i) {
            int g0 = i * 256 + wave * 64;
            __builtin_amdgcn_global_load_lds(
                (const __attribute__((address_space(1))) void*)(src + (size_t)(g0 + lane) * 16),
                (__attribute__((address_space(3))) void*)(bb + g0 * 16), 16, 0, 0);
        }
        if (wave < 2) {
            int g0 = 1024 + wave * 64;
            __builtin_amdgcn_global_load_lds(
                (const __attribute__((address_space(1))) void*)(src + (size_t)(g0 + lane) * 16),
                (__attribute__((address_space(3))) void*)(bb + g0 * 16), 16, 0, 0);
        }
    };
    f32x16 zero16;
    #pragma unroll
    for (int e = 0; e < 16; ++e) zero16[e] = 0.f;
    f32x16 acc[2][2];
    acc[0][0] = zero16; acc[0][1] = zero16; acc[1][0] = zero16; acc[1][1] = zero16;
    auto mfma_phase = [&](int hc) {
        const char* ab = s_all + A_OFF(hc & 1);
        const char* bb = s_all + B_OFF(hc & 1);
        #pragma unroll
        for (int tap = 0; tap < 9; ++tap) {
            const int kh = tap / 3, kw = tap % 3;
            bf16x8 Bf0 = *(const bf16x8*)(bb + (size_t)((tap * 2 + hw) * 64 +      l31) * 16);
            bf16x8 Bf1 = *(const bf16x8*)(bb + (size_t)((tap * 2 + hw) * 64 + 32 + l31) * 16);
            bf16x8 Af0 = *(const bf16x8*)(ab + (wrow + kh) * 4224 + swz(wcb +      l31 + kw + 1, hw));
            bf16x8 Af1 = *(const bf16x8*)(ab + (wrow + kh) * 4224 + swz(wcb + 32 + l31 + kw + 1, hw));
            __builtin_amdgcn_s_setprio(1);
            acc[0][0] = __builtin_amdgcn_mfma_f32_32x32x16_bf16(Af0, Bf0, acc[0][0], 0, 0, 0);
            acc[0][1] = __builtin_amdgcn_mfma_f32_32x32x16_bf16(Af0, Bf1, acc[0][1], 0, 0, 0);
            acc[1][0] = __builtin_amdgcn_mfma_f32_32x32x16_bf16(Af1, Bf0, acc[1][0], 0, 0, 0);
            acc[1][1] = __builtin_amdgcn_mfma_f32_32x32x16_bf16(Af1, Bf1, acc[1][1], 0, 0, 0);
            __builtin_amdgcn_s_setprio(0);
        }
    };
    issueA(0, Ra, Ea);
    issueB(0);
    issueA(1, Rb, Eb);
    __builtin_amdgcn_sched_barrier(0);
    writeA(0, Ra, Ea);
    asm volatile("s_waitcnt vmcnt(9) lgkmcnt(0)" ::: "memory");
    __builtin_amdgcn_s_barrier();
    __builtin_amdgcn_sched_barrier(0);
    #pragma unroll 1
    for (int h = 0; h < 7; ++h) {
        issueB(h + 1);
        if (h < 6) { if (h & 1) issueA(h + 2, Rb, Eb); else issueA(h + 2, Ra, Ea); }
        __builtin_amdgcn_sched_barrier(0);
        mfma_phase(h);
        __builtin_amdgcn_sched_barrier(0);
        if (h & 1) writeA(h + 1, Ra, Ea); else writeA(h + 1, Rb, Eb);
        if (h < 6) asm volatile("s_waitcnt vmcnt(9) lgkmcnt(0)" ::: "memory");
        else       asm volatile("s_waitcnt vmcnt(0) lgkmcnt(0)" ::: "memory");
        __builtin_amdgcn_s_barrier();
        __builtin_amdgcn_sched_barrier(0);
    }
    mfma_phase(7);
    __syncthreads();
    __bf16* X = (__bf16*)s_all;
    #pragma unroll
    for (int mt = 0; mt < 2; ++mt)
        #pragma unroll
        for (int nt = 0; nt < 2; ++nt)
            #pragma unroll
            for (int r = 0; r < 16; ++r) {
                float v = fmaxf(acc[mt][nt][r], 0.f);
                int mrow = (r & 3) + 8 * (r >> 2) + 4 * hw;
                int pxb  = wave * 64 + mt * 32 + mrow;
                int chn  = nt * 32 + l31;
                *(__bf16*)((char*)X + pxb * 128 + ((chn * 2) ^ ((pxb & 7) << 4))) = (__bf16)v;
            }
    const char* s_wc = s_all + 70656;
    const float* s_bias = (const float*)(s_all + 74752);
    f32x16 acc2[2];
    acc2[0] = zero16; acc2[1] = zero16;
    #pragma unroll
    for (int ks = 0; ks < 4; ++ks) {
        int ch0 = ks * 16 + hw * 8;
        bf16x8 a2 = *(const bf16x8*)(s_wc + l31 * 128 + ((ch0 * 2) ^ ((l31 & 7) << 4)));
        #pragma unroll
        for (int nt = 0; nt < 2; ++nt) {
            int pxb  = wave * 64 + nt * 32 + l31;
            bf16x8 b2 = *(const bf16x8*)((const char*)X + pxb * 128 + ((ch0 * 2) ^ ((pxb & 7) << 4)));
            acc2[nt] = __builtin_amdgcn_mfma_f32_32x32x16_bf16(a2, b2, acc2[nt], 0, 0, 0);
        }
    }
    const int h = h0 + wrow;
    #pragma unroll
    for (int nt = 0; nt < 2; ++nt) {
        int wg2 = w0 + wcb + nt * 32 + l31;
        #pragma unroll
        for (int r = 0; r < 16; ++r) {
            int och = (r & 3) + 8 * (r >> 2) + 4 * hw;
            if (och < 20) {
                float v = acc2[nt][r] + s_bias[och];
                if (och >= 16) v = 1.f / (1.f + __expf(-v));
                out[(((size_t)bz * 20 + och) * 512 + h) * 512 + wg2] = v;
            }
        }
    }
}

extern "C" void kernel_launch(void* const* d_in, const int* in_sizes, int n_in,
                              void* d_out, int out_size, void* d_ws, size_t ws_size,
                              hipStream_t stream) {
    const float* feature  = (const float*)d_in[0];
    const float* w_shared = (const float*)d_in[1];
    const float* w_cls = (const float*)d_in[2];
    const float* b_cls = (const float*)d_in[3];
    const float* w_box = (const float*)d_in[4];
    const float* b_box = (const float*)d_in[5];
    const float* w_dir = (const float*)d_in[6];
    const float* b_dir = (const float*)d_in[7];
    const float* w_scr = (const float*)d_in[8];
    const float* b_scr = (const float*)d_in[9];
    float* out = (float*)d_out;
    __bf16* ws3 = (__bf16*)d_ws;   // 147456 B

    prep_w_kernel<<<288, 256, 0, stream>>>(w_shared, ws3);

    const size_t need = (size_t)FT_OFF + FT_BYTES;
    if (ws_size >= need) {
        hipMemsetAsync((char*)d_ws + ZB_OFF, 0, 64, stream);
        char* ft = (char*)d_ws + FT_OFF;
        const char* zbuf = (const char*)d_ws + ZB_OFF;
        for (int bz = 0; bz < 4; ++bz) {
            prep_t_kernel<<<4096, 256, 0, stream>>>(feature, (__bf16*)ft, bz);
            det_main_t<<<512, 512, 0, stream>>>(ft, zbuf, ws3,
                                                w_cls, b_cls, w_box, b_box,
                                                w_dir, b_dir, w_scr, b_scr, out, bz);
        }
    } else {
        det_main_fb<<<4096, 256, 0, stream>>>(feature, ws3,
                                              w_cls, b_cls, w_box, b_box,
                                              w_dir, b_dir, w_scr, b_scr, out);
    }
}

// Round 7
// 227.824 us; speedup vs baseline: 1.5194x; 1.5194x over previous
//
#include <hip/hip_runtime.h>
#include <cstdint>
#include <cstddef>

// ---------------------------------------------------------------------------
// DetCenterDense: fused conv3x3(128->64)+ReLU -> 4x conv1x1 heads (20 ch total,
// sigmoid on last 4) over [4,128,512,512] fp32, NCHW. bf16 MFMA implicit GEMM.
// R7: occupancy push on the R4 structure. LDS 75->52 KB (B single-buffered,
//     head-weights staged post-loop into dead B region) -> 3 blocks/CU;
//     prefetch 2-deep -> 1-deep (-34 VGPR) -> 3 waves/SIMD; 12 waves/CU.
//     2 barriers/hc; A(h+2) loads stay in flight across both (vmcnt(9)).
// ---------------------------------------------------------------------------

typedef __bf16 bf16x8 __attribute__((ext_vector_type(8)));
typedef float f32x16 __attribute__((ext_vector_type(16)));
typedef float f32x4v __attribute__((ext_vector_type(4)));
typedef float f32x2v __attribute__((ext_vector_type(2)));

#define CHW (512 * 512)

// A-tile LDS swizzle (validated R3-R5): granule 16B at (slot s, octet o):
//   lin = s*32 + o*16 ; byte = lin ^ ((lin>>1)&0x10) ^ ((lin>>2)&0x60)
__device__ __forceinline__ int swz(int s, int o) {
    int lin = (s << 5) | (o << 4);
    return lin ^ ((lin >> 1) & 0x10) ^ ((lin >> 2) & 0x60);
}

// ---------------------------------------------------------------------------
// Prepass: repack w_shared [64][128][3][3] fp32 -> bf16, per-half-chunk
// contiguous: ws3 [hc(8)][tap(9)][hw(2)][och(64)][8 bf16]  (18432 B per hc)
// ---------------------------------------------------------------------------
__global__ void prep_w_kernel(const float* __restrict__ w, __bf16* __restrict__ ws3) {
    int idx = blockIdx.x * 256 + threadIdx.x;
    if (idx >= 64 * 128 * 9) return;
    int tap = idx % 9;
    int cin = (idx / 9) % 128;
    int och = idx / (9 * 128);
    int hc = cin >> 4;
    int hw = (cin >> 3) & 1;
    int j  = cin & 7;
    int dst = (((hc * 9 + tap) * 2 + hw) * 64 + och) * 8 + j;
    ws3[dst] = (__bf16)w[idx];
}

// LDS map (bytes), total 52224 -> 3 blocks/CU (156672 <= 163840):
//   A0 @ 0 [16896]   A1 @ 16896 [16896]   ([4 rows][132 slots x 32B], swz)
//   B  @ 33792 [18432] single buf: [tap 9][hw 2][och 64][8 bf16], linear.
//   After main loop: wc overlays @33792 [4096], bias @37888 [128]; X tile @0.
#define A_OFF(p)  ((p) ? 16896 : 0)
#define B_BASE    33792
#define WC_BASE   33792
#define BIAS_BASE 37888

__global__ __launch_bounds__(256, 3)
void det_main_kernel(const float* __restrict__ feature,
                     const __bf16* __restrict__ ws3,
                     const float* __restrict__ w_cls, const float* __restrict__ b_cls,
                     const float* __restrict__ w_box, const float* __restrict__ b_box,
                     const float* __restrict__ w_dir, const float* __restrict__ b_dir,
                     const float* __restrict__ w_scr, const float* __restrict__ b_scr,
                     float* __restrict__ out) {
    __shared__ __align__(1024) char s_all[52224];

    const int tid  = threadIdx.x;
    const int lane = tid & 63;
    const int wave = tid >> 6;
    const int l31  = lane & 31;
    const int hw   = lane >> 5;
    const int wrow = wave >> 1;
    const int wcb  = (wave & 1) * 64;

    // XCD-aware decode: 4096 blocks -> 8 chunks of 512; vertical neighbors
    // (sharing halo rows) schedule-adjacent within an XCD.
    const int bid = blockIdx.x;
    const int wg  = (bid & 7) * 512 + (bid >> 3);
    const int ck  = wg >> 9;
    const int bz  = ck >> 1;
    const int rem = wg & 511;
    const int h0  = (rem >> 1) * 2;
    const int w0  = ((ck & 1) * 2 + (rem & 1)) * 128;

    // ---- staging roles (R4-validated) ----
    // main: thread covers (cin octet m_hw, slot-quad m_q, row m_row): 8 dwordx4
    const int m_hw  = tid & 1;
    const int m_q   = (tid >> 1) & 31;
    const int m_row = tid >> 6;
    const int m_h   = h0 - 1 + m_row;
    const bool m_ok = (unsigned)m_h < 512u;
    const float* m_base = feature + (size_t)(bz * 128 + m_hw * 8) * CHW
                        + (size_t)(m_ok ? m_h : 0) * 512 + (w0 + 4 * m_q);
    // edge: even lanes of every wave (uniform per-wave instr count): 1 dwordx2
    const bool e_on = (tid & 1) == 0;
    const int e_idx = tid >> 1;
    const int e_ee  = (e_idx >> 6) & 1;
    const int e_row = (e_idx >> 4) & 3;
    const int e_cin = e_idx & 15;
    const int e_h   = h0 - 1 + e_row;
    const int e_w   = e_ee ? (w0 + 128) : (w0 - 2);
    const bool e_ok = ((unsigned)e_h < 512u) && ((unsigned)e_w < 511u);
    const float* e_base = feature + (size_t)(bz * 128 + e_cin) * CHW
                        + (size_t)(e_ok ? e_h : 0) * 512 + (e_ok ? e_w : 0);

    f32x4v R[8];      // 1-deep A prefetch (32 VGPR)
    f32x2v E;

    // issue A-loads for half-chunk hc: ALWAYS 9 vmem instrs per wave.
    auto issueA = [&](int hc) {
        const float* p = m_base + (size_t)(hc * 16) * CHW;
        #pragma unroll
        for (int j = 0; j < 8; ++j) R[j] = *(const f32x4v*)(p + (size_t)j * CHW);
        if (e_on) E = *(const f32x2v*)(e_base + (size_t)(hc * 16) * CHW);
    };

    // convert + ds_write into A-buf[hc&1]; zero OOB here (no vmem).
    auto writeA = [&](int hc) {
        char* ab = s_all + A_OFF(hc & 1);
        #pragma unroll
        for (int k = 0; k < 4; ++k) {
            bf16x8 g;
            #pragma unroll
            for (int j = 0; j < 8; ++j) g[j] = (__bf16)(m_ok ? R[j][k] : 0.f);
            *(bf16x8*)(ab + m_row * 4224 + swz(2 + 4 * m_q + k, m_hw)) = g;
        }
        if (e_on) {
            char* b2 = ab + e_row * 4224 + (e_cin & 7) * 2;
            int s0 = e_ee ? 130 : 0;
            *(__bf16*)(b2 + swz(s0,     e_cin >> 3)) = (__bf16)(e_ok ? E[0] : 0.f);
            *(__bf16*)(b2 + swz(s0 + 1, e_cin >> 3)) = (__bf16)(e_ok ? E[1] : 0.f);
        }
    };

    // async global->LDS of hc's weights into single B buffer (1152 x 16B).
    auto issueB = [&](int hc) {
        char* bb = s_all + B_BASE;
        const char* src = (const char*)ws3 + hc * 18432;
        #pragma unroll
        for (int i = 0; i < 4; ++i) {
            int g0 = i * 256 + wave * 64;
            __builtin_amdgcn_global_load_lds(
                (const __attribute__((address_space(1))) void*)(src + (size_t)(g0 + lane) * 16),
                (__attribute__((address_space(3))) void*)(bb + g0 * 16), 16, 0, 0);
        }
        if (wave < 2) {
            int g0 = 1024 + wave * 64;
            __builtin_amdgcn_global_load_lds(
                (const __attribute__((address_space(1))) void*)(src + (size_t)(g0 + lane) * 16),
                (__attribute__((address_space(3))) void*)(bb + g0 * 16), 16, 0, 0);
        }
    };

    f32x16 zero16;
    #pragma unroll
    for (int e = 0; e < 16; ++e) zero16[e] = 0.f;
    f32x16 acc[2][2];
    acc[0][0] = zero16; acc[0][1] = zero16; acc[1][0] = zero16; acc[1][1] = zero16;

    auto mfma_phase = [&](int hc) {
        const char* ab = s_all + A_OFF(hc & 1);
        const char* bb = s_all + B_BASE;
        #pragma unroll
        for (int tap = 0; tap < 9; ++tap) {
            const int kh = tap / 3, kw = tap % 3;
            bf16x8 Bf0 = *(const bf16x8*)(bb + (size_t)((tap * 2 + hw) * 64 +      l31) * 16);
            bf16x8 Bf1 = *(const bf16x8*)(bb + (size_t)((tap * 2 + hw) * 64 + 32 + l31) * 16);
            bf16x8 Af0 = *(const bf16x8*)(ab + (wrow + kh) * 4224 + swz(wcb +      l31 + kw + 1, hw));
            bf16x8 Af1 = *(const bf16x8*)(ab + (wrow + kh) * 4224 + swz(wcb + 32 + l31 + kw + 1, hw));
            __builtin_amdgcn_s_setprio(1);
            acc[0][0] = __builtin_amdgcn_mfma_f32_32x32x16_bf16(Af0, Bf0, acc[0][0], 0, 0, 0);
            acc[0][1] = __builtin_amdgcn_mfma_f32_32x32x16_bf16(Af0, Bf1, acc[0][1], 0, 0, 0);
            acc[1][0] = __builtin_amdgcn_mfma_f32_32x32x16_bf16(Af1, Bf0, acc[1][0], 0, 0, 0);
            acc[1][1] = __builtin_amdgcn_mfma_f32_32x32x16_bf16(Af1, Bf1, acc[1][1], 0, 0, 0);
            __builtin_amdgcn_s_setprio(0);
        }
    };

    // ---- prologue: B(0) DMA'd, A(0) staged, A(1) left in flight ----
    issueB(0);
    issueA(0);
    writeA(0);                     // reg-deps drain A(0); in-order => B(0) too
    issueA(1);
    __builtin_amdgcn_sched_barrier(0);
    asm volatile("s_waitcnt vmcnt(9) lgkmcnt(0)" ::: "memory");  // A(1) in flight
    __builtin_amdgcn_s_barrier();
    __builtin_amdgcn_sched_barrier(0);

    // ---- main loop: 8 half-chunks of 16 cin, 2 barriers each ----
    #pragma unroll 1
    for (int h = 0; h < 8; ++h) {
        mfma_phase(h);
        __builtin_amdgcn_sched_barrier(0);
        __builtin_amdgcn_s_barrier();            // bar1: A(h),B(h) readers done
        __builtin_amdgcn_sched_barrier(0);
        if (h == 7) break;
        issueB(h + 1);                           // overwrite B (safe after bar1)
        writeA(h + 1);                           // into A-buf[(h+1)&1]
        if (h < 6) issueA(h + 2);
        if (h < 6) asm volatile("s_waitcnt vmcnt(9) lgkmcnt(0)" ::: "memory");
        else       asm volatile("s_waitcnt vmcnt(0) lgkmcnt(0)" ::: "memory");
        __builtin_amdgcn_s_barrier();            // bar2: A(h+1),B(h+1) ready
        __builtin_amdgcn_sched_barrier(0);
    }

    // ---- ReLU -> bf16 X tile in LDS (reuse A region @0), px-XOR swizzled ----
    __bf16* X = (__bf16*)s_all;                  // [256 px][64 ch] = 32 KB
    #pragma unroll
    for (int mt = 0; mt < 2; ++mt) {
        #pragma unroll
        for (int nt = 0; nt < 2; ++nt) {
            #pragma unroll
            for (int r = 0; r < 16; ++r) {
                float v = fmaxf(acc[mt][nt][r], 0.f);
                int mrow = (r & 3) + 8 * (r >> 2) + 4 * hw;
                int pxb  = wave * 64 + mt * 32 + mrow;
                int chn  = nt * 32 + l31;
                *(__bf16*)((char*)X + pxb * 128 + ((chn * 2) ^ ((pxb & 7) << 4))) = (__bf16)v;
            }
        }
    }

    // ---- stage 1x1-head weights + bias (post-loop, into dead B region) ----
    {
        char* s_wc = s_all + WC_BASE;
        float* s_bias = (float*)(s_all + BIAS_BASE);
        int och = tid >> 3;
        int j8  = (tid & 7) * 8;
        float v[8];
        if (och < 20) {
            const float* src = (och < 2)  ? (w_cls + och * 64)
                             : (och < 8)  ? (w_box + (och - 2) * 64)
                             : (och < 16) ? (w_dir + (och - 8) * 64)
                                          : (w_scr + (och - 16) * 64);
            #pragma unroll
            for (int j = 0; j < 8; ++j) v[j] = src[j8 + j];
        } else {
            #pragma unroll
            for (int j = 0; j < 8; ++j) v[j] = 0.f;
        }
        bf16x8 wv;
        #pragma unroll
        for (int j = 0; j < 8; ++j) wv[j] = (__bf16)v[j];
        *(bf16x8*)(s_wc + och * 128 + ((j8 * 2) ^ ((och & 7) << 4))) = wv;
        if (tid < 32) {
            s_bias[tid] = (tid < 2)  ? b_cls[tid]
                        : (tid < 8)  ? b_box[tid - 2]
                        : (tid < 16) ? b_dir[tid - 8]
                        : (tid < 20) ? b_scr[tid - 16] : 0.f;
        }
    }
    __syncthreads();   // wc/bias visible to all waves (X is wave-local)

    // ---- stage 2: out[och(20->32)][px] = Wc @ X, K=64 ----
    const char* s_wc = s_all + WC_BASE;
    const float* s_bias = (const float*)(s_all + BIAS_BASE);
    f32x16 acc2[2];
    acc2[0] = zero16; acc2[1] = zero16;
    #pragma unroll
    for (int ks = 0; ks < 4; ++ks) {
        int ch0 = ks * 16 + hw * 8;
        bf16x8 a2 = *(const bf16x8*)(s_wc + l31 * 128 + ((ch0 * 2) ^ ((l31 & 7) << 4)));
        #pragma unroll
        for (int nt = 0; nt < 2; ++nt) {
            int pxb = wave * 64 + nt * 32 + l31;
            bf16x8 b2 = *(const bf16x8*)((const char*)X + pxb * 128 + ((ch0 * 2) ^ ((pxb & 7) << 4)));
            acc2[nt] = __builtin_amdgcn_mfma_f32_32x32x16_bf16(a2, b2, acc2[nt], 0, 0, 0);
        }
    }

    // ---- epilogue: bias, sigmoid on och 16..19, coalesced stores ----
    const int h = h0 + wrow;
    #pragma unroll
    for (int nt = 0; nt < 2; ++nt) {
        int wg2 = w0 + wcb + nt * 32 + l31;
        #pragma unroll
        for (int r = 0; r < 16; ++r) {
            int och = (r & 3) + 8 * (r >> 2) + 4 * hw;
            if (och < 20) {
                float v = acc2[nt][r] + s_bias[och];
                if (och >= 16) v = 1.f / (1.f + __expf(-v));
                out[(((size_t)bz * 20 + och) * 512 + h) * 512 + wg2] = v;
            }
        }
    }
}

extern "C" void kernel_launch(void* const* d_in, const int* in_sizes, int n_in,
                              void* d_out, int out_size, void* d_ws, size_t ws_size,
                              hipStream_t stream) {
    const float* feature  = (const float*)d_in[0];
    const float* w_shared = (const float*)d_in[1];
    const float* w_cls = (const float*)d_in[2];
    const float* b_cls = (const float*)d_in[3];
    const float* w_box = (const float*)d_in[4];
    const float* b_box = (const float*)d_in[5];
    const float* w_dir = (const float*)d_in[6];
    const float* b_dir = (const float*)d_in[7];
    const float* w_scr = (const float*)d_in[8];
    const float* b_scr = (const float*)d_in[9];
    float* out = (float*)d_out;
    __bf16* ws3 = (__bf16*)d_ws;   // 8 * 18432 B = 147456 B

    prep_w_kernel<<<288, 256, 0, stream>>>(w_shared, ws3);

    det_main_kernel<<<4096, 256, 0, stream>>>(feature, ws3,
                                              w_cls, b_cls, w_box, b_box,
                                              w_dir, b_dir, w_scr, b_scr, out);
}